// Round 1
// baseline (583.705 us; speedup 1.0000x reference)
//
#include <hip/hip_runtime.h>
#include <hip/hip_bf16.h>
#include <stdint.h>

#define NTOK 4096
#define DM   1024
#define NH   16
#define DH   64

typedef __attribute__((ext_vector_type(8))) short bf16x8;
typedef __attribute__((ext_vector_type(4))) float f32x4;
typedef __attribute__((ext_vector_type(4))) unsigned short us4;

__device__ inline unsigned short f2bf(float f) {
  union { float f; unsigned int u; } a;
  a.f = f;
  unsigned int u = a.u;
  u += 0x7fffu + ((u >> 16) & 1u);   // round-to-nearest-even
  return (unsigned short)(u >> 16);
}

__device__ inline void gload_lds16(const void* gsrc, void* ldst) {
  __builtin_amdgcn_global_load_lds(
      (const __attribute__((address_space(1))) void*)(uintptr_t)gsrc,
      (__attribute__((address_space(3))) void*)(unsigned int)(uintptr_t)ldst,
      16, 0, 0);
}

// ---------------- f32 -> bf16 conversion ----------------
__global__ void cvt_kernel(const float* __restrict__ in,
                           unsigned short* __restrict__ out, int n4) {
  int i = blockIdx.x * 256 + threadIdx.x;
  if (i < n4) {
    float4 v = ((const float4*)in)[i];
    us4 o;
    o[0] = f2bf(v.x); o[1] = f2bf(v.y); o[2] = f2bf(v.z); o[3] = f2bf(v.w);
    ((us4*)out)[i] = o;
  }
}

// ---------------- GEMM: C[m][n] = sum_k A[m][k]*B[n][k] (+epilogue) ----------
// EPI 0: Cb[m][n] = bf16(acc + bias[n])
// EPI 1: Cb[n][m] = bf16(acc + bias[n])   (transposed store, for V^T)
// EPI 2: Cf[m][n] = acc + bias[n] + resid[m][n]   (f32 final)
template<int EPI>
__global__ __launch_bounds__(256)
void gemm_bt(const unsigned short* __restrict__ A,
             const unsigned short* __restrict__ B,
             const float* __restrict__ bias,
             const float* __restrict__ resid,
             unsigned short* __restrict__ Cb,
             float* __restrict__ Cf,
             int M, int Nout, int K)
{
  const int tid  = threadIdx.x;
  const int wid  = tid >> 6;
  const int lane = tid & 63;
  const int bn = blockIdx.x * 128;
  const int bm = blockIdx.y * 128;
  const int wr = wid >> 1;
  const int wc = wid & 1;

  __shared__ __align__(16) unsigned short As[128 * 32];
  __shared__ __align__(16) unsigned short Bs[128 * 32];

  f32x4 acc[4][4];
#pragma unroll
  for (int i = 0; i < 4; i++)
#pragma unroll
    for (int j = 0; j < 4; j++) acc[i][j] = f32x4{0.f, 0.f, 0.f, 0.f};

  const int fr = lane & 15;
  const int fk = (lane >> 4) * 8;
  const int srow = lane >> 2;        // 0..15 within chunk
  const int scol = (lane & 3) * 8;   // bf16 col offset

  for (int k0 = 0; k0 < K; k0 += 32) {
#pragma unroll
    for (int c = 0; c < 2; ++c) {
      const int chunk = wid * 2 + c;             // 0..7
      gload_lds16(A + (size_t)(bm + chunk * 16 + srow) * K + k0 + scol,
                  &As[chunk * 512]);
      gload_lds16(B + (size_t)(bn + chunk * 16 + srow) * K + k0 + scol,
                  &Bs[chunk * 512]);
    }
    __syncthreads();
    bf16x8 af[4], bfr[4];
#pragma unroll
    for (int i = 0; i < 4; i++)
      af[i] = *(const bf16x8*)&As[(wr * 64 + i * 16 + fr) * 32 + fk];
#pragma unroll
    for (int j = 0; j < 4; j++)
      bfr[j] = *(const bf16x8*)&Bs[(wc * 64 + j * 16 + fr) * 32 + fk];
#pragma unroll
    for (int i = 0; i < 4; i++)
#pragma unroll
      for (int j = 0; j < 4; j++)
        acc[i][j] = __builtin_amdgcn_mfma_f32_16x16x32_bf16(af[i], bfr[j],
                                                            acc[i][j], 0, 0, 0);
    __syncthreads();
  }

  const int fq = lane >> 4;
#pragma unroll
  for (int j = 0; j < 4; j++) {
    const int col = bn + wc * 64 + j * 16 + fr;
    const float bv = bias[col];
#pragma unroll
    for (int i = 0; i < 4; i++) {
      const int row0 = bm + wr * 64 + i * 16 + fq * 4;
      if constexpr (EPI == 0) {
#pragma unroll
        for (int r = 0; r < 4; r++)
          Cb[(size_t)(row0 + r) * Nout + col] = f2bf(acc[i][j][r] + bv);
      } else if constexpr (EPI == 1) {
        us4 pk;
#pragma unroll
        for (int r = 0; r < 4; r++) pk[r] = f2bf(acc[i][j][r] + bv);
        *(us4*)&Cb[(size_t)col * M + row0] = pk;
      } else {
#pragma unroll
        for (int r = 0; r < 4; r++) {
          const size_t idx = (size_t)(row0 + r) * Nout + col;
          Cf[idx] = acc[i][j][r] + bv + resid[idx];
        }
      }
    }
  }
}

// ---------------- flash attention with per-key bias ----------------
// Q,K: bf16 [NTOK][DM]; Vt: bf16 [DM][NTOK]; out O: bf16 [NTOK][DM]
__global__ __launch_bounds__(256)
void attn_kernel(const unsigned short* __restrict__ Q,
                 const unsigned short* __restrict__ K,
                 const unsigned short* __restrict__ Vt,
                 const float* __restrict__ hbias,
                 unsigned short* __restrict__ O)
{
  const int head = blockIdx.y;
  const int qb   = blockIdx.x * 64;
  const int tid  = threadIdx.x;
  const int wid  = tid >> 6;
  const int lane = tid & 63;

  __shared__ __align__(16) float hs[NTOK];
  __shared__ __align__(16) unsigned short ps[4][16 * 32];

  for (int i = tid; i < NTOK / 4; i += 256)
    ((float4*)hs)[i] = ((const float4*)hbias)[i];
  __syncthreads();

  const int fr = lane & 15;
  const int fg = lane >> 4;

  const unsigned short* qrow = Q + (size_t)(qb + wid * 16 + fr) * DM + head * DH;
  const bf16x8 qf0 = *(const bf16x8*)(qrow + fg * 8);
  const bf16x8 qf1 = *(const bf16x8*)(qrow + 32 + fg * 8);

  float m[4], l[4];
  f32x4 o[4];
#pragma unroll
  for (int r = 0; r < 4; r++) { m[r] = -3.0e38f; l[r] = 0.f; }
#pragma unroll
  for (int t = 0; t < 4; t++) o[t] = f32x4{0.f, 0.f, 0.f, 0.f};

  const float scale = 0.125f;  // 1/sqrt(64)
  unsigned short* pw = &ps[wid][0];

  for (int kt = 0; kt < NTOK; kt += 32) {
    f32x4 s0 = f32x4{0.f, 0.f, 0.f, 0.f};
    f32x4 s1 = f32x4{0.f, 0.f, 0.f, 0.f};
    {
      const unsigned short* kr0 = K + (size_t)(kt + fr) * DM + head * DH;
      const unsigned short* kr1 = K + (size_t)(kt + 16 + fr) * DM + head * DH;
      const bf16x8 k00 = *(const bf16x8*)(kr0 + fg * 8);
      const bf16x8 k01 = *(const bf16x8*)(kr0 + 32 + fg * 8);
      const bf16x8 k10 = *(const bf16x8*)(kr1 + fg * 8);
      const bf16x8 k11 = *(const bf16x8*)(kr1 + 32 + fg * 8);
      s0 = __builtin_amdgcn_mfma_f32_16x16x32_bf16(qf0, k00, s0, 0, 0, 0);
      s0 = __builtin_amdgcn_mfma_f32_16x16x32_bf16(qf1, k01, s0, 0, 0, 0);
      s1 = __builtin_amdgcn_mfma_f32_16x16x32_bf16(qf0, k10, s1, 0, 0, 0);
      s1 = __builtin_amdgcn_mfma_f32_16x16x32_bf16(qf1, k11, s1, 0, 0, 0);
    }
    const float hb0 = hs[kt + fr];
    const float hb1 = hs[kt + 16 + fr];
    float p0[4], p1[4], tm[4], rs[4], al4[4];
#pragma unroll
    for (int r = 0; r < 4; r++) {
      s0[r] = s0[r] * scale - hb0;
      s1[r] = s1[r] * scale - hb1;
      tm[r] = fmaxf(s0[r], s1[r]);
    }
#pragma unroll
    for (int d = 1; d < 16; d <<= 1)
#pragma unroll
      for (int r = 0; r < 4; r++)
        tm[r] = fmaxf(tm[r], __shfl_xor(tm[r], d, 64));
#pragma unroll
    for (int r = 0; r < 4; r++) {
      const float mn = fmaxf(m[r], tm[r]);
      al4[r] = __expf(m[r] - mn);
      m[r] = mn;
      p0[r] = __expf(s0[r] - mn);
      p1[r] = __expf(s1[r] - mn);
      rs[r] = p0[r] + p1[r];
    }
#pragma unroll
    for (int d = 1; d < 16; d <<= 1)
#pragma unroll
      for (int r = 0; r < 4; r++) rs[r] += __shfl_xor(rs[r], d, 64);
#pragma unroll
    for (int r = 0; r < 4; r++) l[r] = l[r] * al4[r] + rs[r];
#pragma unroll
    for (int t = 0; t < 4; t++)
#pragma unroll
      for (int r = 0; r < 4; r++) o[t][r] *= al4[r];

    // transpose P through per-wave LDS into A-fragment layout
#pragma unroll
    for (int r = 0; r < 4; r++) {
      const int row = fg * 4 + r;
      pw[row * 32 + fr]      = f2bf(p0[r]);
      pw[row * 32 + 16 + fr] = f2bf(p1[r]);
    }
    const bf16x8 pa = *(const bf16x8*)&pw[fr * 32 + fg * 8];
#pragma unroll
    for (int t = 0; t < 4; t++) {
      const unsigned short* vr =
          Vt + (size_t)(head * DH + t * 16 + fr) * NTOK + kt + fg * 8;
      const bf16x8 vf = *(const bf16x8*)vr;
      o[t] = __builtin_amdgcn_mfma_f32_16x16x32_bf16(pa, vf, o[t], 0, 0, 0);
    }
  }

#pragma unroll
  for (int r = 0; r < 4; r++) {
    const float inv = 1.0f / l[r];
    const int row = qb + wid * 16 + fg * 4 + r;
#pragma unroll
    for (int t = 0; t < 4; t++)
      O[(size_t)row * DM + head * DH + t * 16 + fr] = f2bf(o[t][r] * inv);
  }
}

extern "C" void kernel_launch(void* const* d_in, const int* in_sizes, int n_in,
                              void* d_out, int out_size, void* d_ws, size_t ws_size,
                              hipStream_t stream) {
  const float* x  = (const float*)d_in[0];
  const float* h  = (const float*)d_in[1];
  const float* Wq = (const float*)d_in[2];
  const float* bq = (const float*)d_in[3];
  const float* Wk = (const float*)d_in[4];
  const float* bk = (const float*)d_in[5];
  const float* Wv = (const float*)d_in[6];
  const float* bv = (const float*)d_in[7];
  const float* Wo = (const float*)d_in[8];
  const float* bo = (const float*)d_in[9];
  float* out = (float*)d_out;

  char* ws = (char*)d_ws;
  const size_t MB = 1 << 20;
  unsigned short* xb  = (unsigned short*)(ws + 0 * MB);   // 8 MB
  unsigned short* wqb = (unsigned short*)(ws + 8 * MB);   // 2 MB
  unsigned short* wkb = (unsigned short*)(ws + 10 * MB);  // 2 MB
  unsigned short* wvb = (unsigned short*)(ws + 12 * MB);  // 2 MB
  unsigned short* wob = (unsigned short*)(ws + 14 * MB);  // 2 MB
  unsigned short* Qb  = (unsigned short*)(ws + 16 * MB);  // 8 MB
  unsigned short* Kb  = (unsigned short*)(ws + 24 * MB);  // 8 MB
  unsigned short* Vtb = (unsigned short*)(ws + 32 * MB);  // 8 MB  (transposed V)
  unsigned short* AOb = (unsigned short*)(ws + 40 * MB);  // 8 MB

  // f32 -> bf16 conversions
  cvt_kernel<<<4096, 256, 0, stream>>>(x,  xb,  (NTOK * DM) / 4);
  cvt_kernel<<<1024, 256, 0, stream>>>(Wq, wqb, (DM * DM) / 4);
  cvt_kernel<<<1024, 256, 0, stream>>>(Wk, wkb, (DM * DM) / 4);
  cvt_kernel<<<1024, 256, 0, stream>>>(Wv, wvb, (DM * DM) / 4);
  cvt_kernel<<<1024, 256, 0, stream>>>(Wo, wob, (DM * DM) / 4);

  dim3 gg(DM / 128, NTOK / 128);
  gemm_bt<0><<<gg, 256, 0, stream>>>(xb, wqb, bq, nullptr, Qb,  nullptr, NTOK, DM, DM);
  gemm_bt<0><<<gg, 256, 0, stream>>>(xb, wkb, bk, nullptr, Kb,  nullptr, NTOK, DM, DM);
  gemm_bt<1><<<gg, 256, 0, stream>>>(xb, wvb, bv, nullptr, Vtb, nullptr, NTOK, DM, DM);

  attn_kernel<<<dim3(NTOK / 64, NH), 256, 0, stream>>>(Qb, Kb, Vtb, h, AOb);

  gemm_bt<2><<<gg, 256, 0, stream>>>(AOb, wob, bo, x, nullptr, out, NTOK, DM, DM);
}

// Round 2
// 334.897 us; speedup vs baseline: 1.7429x; 1.7429x over previous
//
#include <hip/hip_runtime.h>
#include <hip/hip_bf16.h>
#include <stdint.h>

#define NTOK 4096
#define DM   1024
#define NH   16
#define DH   64
#define SCL  0.1803368801111129f   /* 0.125 * log2(e) */
#define LOG2E 1.4426950408889634f

typedef __attribute__((ext_vector_type(8)))  short bf16x8;
typedef __attribute__((ext_vector_type(4)))  float f32x4;
typedef __attribute__((ext_vector_type(16))) float f32x16;
typedef __attribute__((ext_vector_type(4)))  unsigned short us4;

__device__ inline unsigned short f2bf(float f) {
  union { float f; unsigned int u; } a;
  a.f = f;
  unsigned int u = a.u;
  u += 0x7fffu + ((u >> 16) & 1u);
  return (unsigned short)(u >> 16);
}

__device__ inline unsigned int cvtpk_bf16(float lo, float hi) {
  unsigned int r;
  asm("v_cvt_pk_bf16_f32 %0, %1, %2" : "=v"(r) : "v"(lo), "v"(hi));
  return r;
}

__device__ inline void gload_lds16(const void* gsrc, void* ldst) {
  __builtin_amdgcn_global_load_lds(
      (const __attribute__((address_space(1))) void*)(uintptr_t)gsrc,
      (__attribute__((address_space(3))) void*)(unsigned int)(uintptr_t)ldst,
      16, 0, 0);
}

// ---------------- f32 -> bf16 conversion ----------------
__global__ void cvt_kernel(const float* __restrict__ in,
                           unsigned short* __restrict__ out, int n4) {
  int i = blockIdx.x * 256 + threadIdx.x;
  if (i < n4) {
    float4 v = ((const float4*)in)[i];
    us4 o;
    o[0] = f2bf(v.x); o[1] = f2bf(v.y); o[2] = f2bf(v.z); o[3] = f2bf(v.w);
    ((us4*)out)[i] = o;
  }
}

// ---------------- h permute: hperm[t*32 + hi*16 + r] = log2e*h[key] --------
__global__ void hprep_kernel(const float* __restrict__ h,
                             float* __restrict__ hperm) {
  int i = blockIdx.x * 256 + threadIdx.x;      // 0..4095
  int r  = i & 15;
  int hi = (i >> 4) & 1;
  int t  = i >> 5;
  int key = t * 32 + (r & 3) + 8 * (r >> 2) + 4 * hi;
  hperm[i] = LOG2E * h[key];                   // GAMMA = 1
}

// ---------------- fused QKV GEMM: A[4096][1024] x Wpack[3072][1024]^T ------
__global__ __launch_bounds__(256)
void gemm_qkv(const unsigned short* __restrict__ A,
              const unsigned short* __restrict__ B,
              const float* __restrict__ bq, const float* __restrict__ bk,
              const float* __restrict__ bv,
              unsigned short* __restrict__ Qb, unsigned short* __restrict__ Kb,
              unsigned short* __restrict__ Vt)
{
  const int tid  = threadIdx.x;
  const int wid  = tid >> 6;
  const int lane = tid & 63;
  const int bn = blockIdx.x * 128;
  const int bm = blockIdx.y * 128;
  const int wr = wid >> 1;
  const int wc = wid & 1;

  __shared__ __align__(16) unsigned short As[128 * 32];
  __shared__ __align__(16) unsigned short Bs[128 * 32];

  f32x4 acc[4][4];
#pragma unroll
  for (int i = 0; i < 4; i++)
#pragma unroll
    for (int j = 0; j < 4; j++) acc[i][j] = f32x4{0.f, 0.f, 0.f, 0.f};

  const int fr = lane & 15;
  const int fk = (lane >> 4) * 8;
  const int srow = lane >> 2;
  const int scol = (lane & 3) * 8;

  for (int k0 = 0; k0 < DM; k0 += 32) {
#pragma unroll
    for (int c = 0; c < 2; ++c) {
      const int chunk = wid * 2 + c;
      gload_lds16(A + (size_t)(bm + chunk * 16 + srow) * DM + k0 + scol,
                  &As[chunk * 512]);
      gload_lds16(B + (size_t)(bn + chunk * 16 + srow) * DM + k0 + scol,
                  &Bs[chunk * 512]);
    }
    __syncthreads();
    bf16x8 af[4], bfr[4];
#pragma unroll
    for (int i = 0; i < 4; i++)
      af[i] = *(const bf16x8*)&As[(wr * 64 + i * 16 + fr) * 32 + fk];
#pragma unroll
    for (int j = 0; j < 4; j++)
      bfr[j] = *(const bf16x8*)&Bs[(wc * 64 + j * 16 + fr) * 32 + fk];
#pragma unroll
    for (int i = 0; i < 4; i++)
#pragma unroll
      for (int j = 0; j < 4; j++)
        acc[i][j] = __builtin_amdgcn_mfma_f32_16x16x32_bf16(af[i], bfr[j],
                                                            acc[i][j], 0, 0, 0);
    __syncthreads();
  }

  const int fq = lane >> 4;
  const int region = bn >> 10;                       // 0=Q 1=K 2=V
  const float* bias = (region == 0) ? bq : (region == 1) ? bk : bv;
  unsigned short* outp = (region == 0) ? Qb : Kb;
#pragma unroll
  for (int j = 0; j < 4; j++) {
    const int col = bn + wc * 64 + j * 16 + fr;
    const int cl  = col & 1023;
    const float bvx = bias[cl];
#pragma unroll
    for (int i = 0; i < 4; i++) {
      const int row0 = bm + wr * 64 + i * 16 + fq * 4;
      if (region < 2) {
#pragma unroll
        for (int r = 0; r < 4; r++)
          outp[(size_t)(row0 + r) * DM + cl] = f2bf(acc[i][j][r] + bvx);
      } else {
        us4 pk;
#pragma unroll
        for (int r = 0; r < 4; r++) pk[r] = f2bf(acc[i][j][r] + bvx);
        *(us4*)&Vt[(size_t)cl * NTOK + row0] = pk;
      }
    }
  }
}

// ---------------- final GEMM: out = AO x Wo^T + bo + x  (f32 out) ----------
__global__ __launch_bounds__(256)
void gemm_out(const unsigned short* __restrict__ A,
              const unsigned short* __restrict__ B,
              const float* __restrict__ bias,
              const float* __restrict__ resid,
              float* __restrict__ Cf)
{
  const int tid  = threadIdx.x;
  const int wid  = tid >> 6;
  const int lane = tid & 63;
  const int bn = blockIdx.x * 128;
  const int bm = blockIdx.y * 128;
  const int wr = wid >> 1;
  const int wc = wid & 1;

  __shared__ __align__(16) unsigned short As[128 * 32];
  __shared__ __align__(16) unsigned short Bs[128 * 32];

  f32x4 acc[4][4];
#pragma unroll
  for (int i = 0; i < 4; i++)
#pragma unroll
    for (int j = 0; j < 4; j++) acc[i][j] = f32x4{0.f, 0.f, 0.f, 0.f};

  const int fr = lane & 15;
  const int fk = (lane >> 4) * 8;
  const int srow = lane >> 2;
  const int scol = (lane & 3) * 8;

  for (int k0 = 0; k0 < DM; k0 += 32) {
#pragma unroll
    for (int c = 0; c < 2; ++c) {
      const int chunk = wid * 2 + c;
      gload_lds16(A + (size_t)(bm + chunk * 16 + srow) * DM + k0 + scol,
                  &As[chunk * 512]);
      gload_lds16(B + (size_t)(bn + chunk * 16 + srow) * DM + k0 + scol,
                  &Bs[chunk * 512]);
    }
    __syncthreads();
    bf16x8 af[4], bfr[4];
#pragma unroll
    for (int i = 0; i < 4; i++)
      af[i] = *(const bf16x8*)&As[(wr * 64 + i * 16 + fr) * 32 + fk];
#pragma unroll
    for (int j = 0; j < 4; j++)
      bfr[j] = *(const bf16x8*)&Bs[(wc * 64 + j * 16 + fr) * 32 + fk];
#pragma unroll
    for (int i = 0; i < 4; i++)
#pragma unroll
      for (int j = 0; j < 4; j++)
        acc[i][j] = __builtin_amdgcn_mfma_f32_16x16x32_bf16(af[i], bfr[j],
                                                            acc[i][j], 0, 0, 0);
    __syncthreads();
  }

  const int fq = lane >> 4;
#pragma unroll
  for (int j = 0; j < 4; j++) {
    const int col = bn + wc * 64 + j * 16 + fr;
    const float bvx = bias[col];
#pragma unroll
    for (int i = 0; i < 4; i++) {
      const int row0 = bm + wr * 64 + i * 16 + fq * 4;
#pragma unroll
      for (int r = 0; r < 4; r++) {
        const size_t idx = (size_t)(row0 + r) * DM + col;
        Cf[idx] = acc[i][j][r] + bvx + resid[idx];
      }
    }
  }
}

// ---------------- attention: swapped-QK^T 32x32, in-register softmax -------
// Q,K bf16 [NTOK][DM]; Vt bf16 [DM][NTOK]; hperm f32 [NTOK]; O bf16 [NTOK][DM]
#define MFMA32(a, b, c) __builtin_amdgcn_mfma_f32_32x32x16_bf16(a, b, c, 0, 0, 0)

__global__ __launch_bounds__(256, 2)
void attn_kernel(const unsigned short* __restrict__ Q,
                 const unsigned short* __restrict__ K,
                 const unsigned short* __restrict__ Vt,
                 const float* __restrict__ hperm,
                 unsigned short* __restrict__ O)
{
  const int head = blockIdx.y;
  const int tid  = threadIdx.x;
  const int wid  = tid >> 6;
  const int lane = tid & 63;
  const int c31  = lane & 31;
  const int hi   = lane >> 5;
  const int qb   = blockIdx.x * 128 + wid * 32;

  // Q fragment (B-operand): lane holds Q[qb+c31][16c + 8*hi + j]
  const unsigned short* qp = Q + (size_t)(qb + c31) * DM + head * DH + hi * 8;
  const bf16x8 qf0 = *(const bf16x8*)(qp);
  const bf16x8 qf1 = *(const bf16x8*)(qp + 16);
  const bf16x8 qf2 = *(const bf16x8*)(qp + 32);
  const bf16x8 qf3 = *(const bf16x8*)(qp + 48);

  const unsigned short* kp = K + (size_t)c31 * DM + head * DH + hi * 8;
  const unsigned short* vp = Vt + (size_t)(head * DH + c31) * NTOK + hi * 8;
  const float* hp = hperm + hi * 16;

  f32x16 o0, o1;
#pragma unroll
  for (int i = 0; i < 16; i++) { o0[i] = 0.f; o1[i] = 0.f; }
  float m = -3.0e38f, l = 0.f;

  // preload tile 0: K fragments + bias
  bf16x8 kf0 = *(const bf16x8*)(kp);
  bf16x8 kf1 = *(const bf16x8*)(kp + 16);
  bf16x8 kf2 = *(const bf16x8*)(kp + 32);
  bf16x8 kf3 = *(const bf16x8*)(kp + 48);
  float4 hb0 = *(const float4*)(hp + 0);
  float4 hb1 = *(const float4*)(hp + 4);
  float4 hb2 = *(const float4*)(hp + 8);
  float4 hb3 = *(const float4*)(hp + 12);

  for (int t = 0; t < NTOK / 32; ++t) {
    const int kt = t * 32;
    // V fragments for this tile (A-operand of PV): latency hidden by QK+softmax
    const unsigned short* vb = vp + kt;
    const bf16x8 v00 = *(const bf16x8*)(vb);
    const bf16x8 v01 = *(const bf16x8*)(vb + 16);
    const bf16x8 v10 = *(const bf16x8*)(vb + (size_t)32 * NTOK);
    const bf16x8 v11 = *(const bf16x8*)(vb + (size_t)32 * NTOK + 16);

    // S^T[key][q] = K . Q^T
    f32x16 s;
#pragma unroll
    for (int i = 0; i < 16; i++) s[i] = 0.f;
    s = MFMA32(kf0, qf0, s);
    s = MFMA32(kf1, qf1, s);
    s = MFMA32(kf2, qf2, s);
    s = MFMA32(kf3, qf3, s);

    // prefetch next tile K + bias
    const int tn = (t + 1 < NTOK / 32) ? t + 1 : t;
    const unsigned short* knp = kp + (size_t)tn * 32 * DM;
    const bf16x8 nf0 = *(const bf16x8*)(knp);
    const bf16x8 nf1 = *(const bf16x8*)(knp + 16);
    const bf16x8 nf2 = *(const bf16x8*)(knp + 32);
    const bf16x8 nf3 = *(const bf16x8*)(knp + 48);
    const float* hnp = hp + tn * 32;
    const float4 nh0 = *(const float4*)(hnp + 0);
    const float4 nh1 = *(const float4*)(hnp + 4);
    const float4 nh2 = *(const float4*)(hnp + 8);
    const float4 nh3 = *(const float4*)(hnp + 12);

    // logits in log2 domain: L = s*SCL - hb
    float Lv[16];
    Lv[0]  = fmaf(s[0],  SCL, -hb0.x); Lv[1]  = fmaf(s[1],  SCL, -hb0.y);
    Lv[2]  = fmaf(s[2],  SCL, -hb0.z); Lv[3]  = fmaf(s[3],  SCL, -hb0.w);
    Lv[4]  = fmaf(s[4],  SCL, -hb1.x); Lv[5]  = fmaf(s[5],  SCL, -hb1.y);
    Lv[6]  = fmaf(s[6],  SCL, -hb1.z); Lv[7]  = fmaf(s[7],  SCL, -hb1.w);
    Lv[8]  = fmaf(s[8],  SCL, -hb2.x); Lv[9]  = fmaf(s[9],  SCL, -hb2.y);
    Lv[10] = fmaf(s[10], SCL, -hb2.z); Lv[11] = fmaf(s[11], SCL, -hb2.w);
    Lv[12] = fmaf(s[12], SCL, -hb3.x); Lv[13] = fmaf(s[13], SCL, -hb3.y);
    Lv[14] = fmaf(s[14], SCL, -hb3.z); Lv[15] = fmaf(s[15], SCL, -hb3.w);

    // in-lane max over 16 + cross-half
    float pm = fmaxf(fmaxf(fmaxf(Lv[0], Lv[1]), fmaxf(Lv[2], Lv[3])),
                     fmaxf(fmaxf(Lv[4], Lv[5]), fmaxf(Lv[6], Lv[7])));
    pm = fmaxf(pm, fmaxf(fmaxf(fmaxf(Lv[8], Lv[9]), fmaxf(Lv[10], Lv[11])),
                         fmaxf(fmaxf(Lv[12], Lv[13]), fmaxf(Lv[14], Lv[15]))));
    pm = fmaxf(pm, __shfl_xor(pm, 32, 64));

    // defer-max (T13): rescale only when max grew past threshold
    if (!__all(pm <= m + 8.0f)) {
      const float mn = fmaxf(m, pm);
      const float al = exp2f(m - mn);
      m = mn;
      l *= al;
#pragma unroll
      for (int i = 0; i < 16; i++) { o0[i] *= al; o1[i] *= al; }
    }

    float ps[16];
#pragma unroll
    for (int r = 0; r < 16; r++) ps[r] = exp2f(Lv[r] - m);
    float rs = (((ps[0] + ps[1]) + (ps[2] + ps[3])) +
                ((ps[4] + ps[5]) + (ps[6] + ps[7]))) +
               (((ps[8] + ps[9]) + (ps[10] + ps[11])) +
                ((ps[12] + ps[13]) + (ps[14] + ps[15])));
    rs += __shfl_xor(rs, 32, 64);
    l += rs;

    // pack P^T into B-fragments via cvt_pk + permlane32_swap (T12)
    unsigned int X1 = cvtpk_bf16(ps[0],  ps[1]);
    unsigned int X2 = cvtpk_bf16(ps[2],  ps[3]);
    unsigned int Y1 = cvtpk_bf16(ps[4],  ps[5]);
    unsigned int Y2 = cvtpk_bf16(ps[6],  ps[7]);
    asm("v_permlane32_swap_b32 %0, %1" : "+v"(X1), "+v"(Y1));
    asm("v_permlane32_swap_b32 %0, %1" : "+v"(X2), "+v"(Y2));
    unsigned int X3 = cvtpk_bf16(ps[8],  ps[9]);
    unsigned int X4 = cvtpk_bf16(ps[10], ps[11]);
    unsigned int Y3 = cvtpk_bf16(ps[12], ps[13]);
    unsigned int Y4 = cvtpk_bf16(ps[14], ps[15]);
    asm("v_permlane32_swap_b32 %0, %1" : "+v"(X3), "+v"(Y3));
    asm("v_permlane32_swap_b32 %0, %1" : "+v"(X4), "+v"(Y4));

    union { unsigned int u[4]; bf16x8 v; } P0, P1;
    P0.u[0] = X1; P0.u[1] = X2; P0.u[2] = Y1; P0.u[3] = Y2;
    P1.u[0] = X3; P1.u[1] = X4; P1.u[2] = Y3; P1.u[3] = Y4;

    // O^T[d][q] += V^T . P^T
    o0 = MFMA32(v00, P0.v, o0);
    o0 = MFMA32(v01, P1.v, o0);
    o1 = MFMA32(v10, P0.v, o1);
    o1 = MFMA32(v11, P1.v, o1);

    kf0 = nf0; kf1 = nf1; kf2 = nf2; kf3 = nf3;
    hb0 = nh0; hb1 = nh1; hb2 = nh2; hb3 = nh3;
  }

  // epilogue: O[q][head*64 + d] = o/l, d = 32*dblk + 8*g + 4*hi + e
  const float inv = 1.0f / l;
  unsigned short* ob = O + (size_t)(qb + c31) * DM + head * DH;
#pragma unroll
  for (int g = 0; g < 4; g++) {
    us4 pk;
    pk[0] = f2bf(o0[4 * g + 0] * inv); pk[1] = f2bf(o0[4 * g + 1] * inv);
    pk[2] = f2bf(o0[4 * g + 2] * inv); pk[3] = f2bf(o0[4 * g + 3] * inv);
    *(us4*)(ob + 8 * g + 4 * hi) = pk;
  }
#pragma unroll
  for (int g = 0; g < 4; g++) {
    us4 pk;
    pk[0] = f2bf(o1[4 * g + 0] * inv); pk[1] = f2bf(o1[4 * g + 1] * inv);
    pk[2] = f2bf(o1[4 * g + 2] * inv); pk[3] = f2bf(o1[4 * g + 3] * inv);
    *(us4*)(ob + 32 + 8 * g + 4 * hi) = pk;
  }
}

extern "C" void kernel_launch(void* const* d_in, const int* in_sizes, int n_in,
                              void* d_out, int out_size, void* d_ws, size_t ws_size,
                              hipStream_t stream) {
  const float* x  = (const float*)d_in[0];
  const float* h  = (const float*)d_in[1];
  const float* Wq = (const float*)d_in[2];
  const float* bq = (const float*)d_in[3];
  const float* Wk = (const float*)d_in[4];
  const float* bk = (const float*)d_in[5];
  const float* Wv = (const float*)d_in[6];
  const float* bv = (const float*)d_in[7];
  const float* Wo = (const float*)d_in[8];
  const float* bo = (const float*)d_in[9];
  float* out = (float*)d_out;

  char* ws = (char*)d_ws;
  const size_t MB = 1 << 20;
  unsigned short* xb    = (unsigned short*)(ws + 0 * MB);   // 8 MB
  unsigned short* wqkvb = (unsigned short*)(ws + 8 * MB);   // 6 MB
  unsigned short* wob   = (unsigned short*)(ws + 14 * MB);  // 2 MB
  unsigned short* Qb    = (unsigned short*)(ws + 16 * MB);  // 8 MB
  unsigned short* Kb    = (unsigned short*)(ws + 24 * MB);  // 8 MB
  unsigned short* Vtb   = (unsigned short*)(ws + 32 * MB);  // 8 MB
  unsigned short* AOb   = (unsigned short*)(ws + 40 * MB);  // 8 MB
  float*          hperm = (float*)(ws + 48 * MB);           // 16 KB

  cvt_kernel<<<4096, 256, 0, stream>>>(x,  xb, (NTOK * DM) / 4);
  cvt_kernel<<<1024, 256, 0, stream>>>(Wq, wqkvb,               (DM * DM) / 4);
  cvt_kernel<<<1024, 256, 0, stream>>>(Wk, wqkvb + DM * DM,     (DM * DM) / 4);
  cvt_kernel<<<1024, 256, 0, stream>>>(Wv, wqkvb + 2 * DM * DM, (DM * DM) / 4);
  cvt_kernel<<<1024, 256, 0, stream>>>(Wo, wob,                 (DM * DM) / 4);
  hprep_kernel<<<16, 256, 0, stream>>>(h, hperm);

  gemm_qkv<<<dim3(24, 32), 256, 0, stream>>>(xb, wqkvb, bq, bk, bv, Qb, Kb, Vtb);

  attn_kernel<<<dim3(NTOK / 128, NH), 256, 0, stream>>>(Qb, Kb, Vtb, hperm, AOb);

  gemm_out<<<dim3(DM / 128, NTOK / 128), 256, 0, stream>>>(AOb, wob, bo, x, out);
}